// Round 7
// baseline (6353.506 us; speedup 1.0000x reference)
//
#include <hip/hip_runtime.h>
#include <hip/hip_bf16.h>

// 5-layer GNN encoder x2 branches + projector + mean-pool + L2norm + logits.
// Round 13: B operand de-LDS'd (direct L2->register fragments). Evidence:
// MfmaUtil pinned ~26% across 3 structures (R3/R4/R6); occupancy 28->39%
// null (R6); sync-structure null (R9/R10). Bottom-up: LDS pipe is the
// largest consumer (~48% busy), 2/3 of it the B operand — pure overhead
// since B (weights, 0.8MB) is L2-resident and re-staged by all 782
// row-blocks. Now B hi/lo fragments load straight from global into regs
// one K-step ahead (same bytes the swizzled-LDS path delivered =>
// bit-identical output, absmax 0.421875); A keeps the proven LDS dbuf +
// __syncthreads 2-phase. LDS 32KB->16KB; VGPR ~110 => launch_bounds(256,4),
// 16 waves/CU (inside the measured 12-20-wave plateau).
// Determinism machinery from round 8 kept (fixed-slot BN psum + two-stage
// reduce, canonical CSR bucket sort).
//
// d_ws layout (bytes):
//   h    bf16 [N,300]  @ 0            pre-BN layer output
//   agg  bf16 [N,320]  @ 60,000,000   K-padded zeros in 300..319
//   hid  bf16 [N,600]  @ 124,000,000  (reused: BN(h) copy; then f-splits for logits)
//   guard 256B zero    @ 244,000,000  (protects GEMM2 last-row K-overrun)
//   f0   f32  [4096,300] @ 244,000,256
//   f1   f32  [4096,300] @ 248,915,456   total 253,830,656
// d_out doubles as scratch (CSR + packed + stats + combo + split weights +
// psum/part2), all consumed before the final logits GEMM overwrites it.

#define EMB 300
#define EMBC 75       // 300/4 chunks (h pitch 300)
#define AGGP 320      // agg row pitch (elems)
#define AGGC 80
#define HID 600
#define NGRAPH 4096
#define BN_EPS 1e-5f
#define INV_TEMP 25.0f
#define NRED 24       // stage-1 stat-reduction blocks

typedef __hip_bfloat16 bf16;
struct __align__(8) bf4 { bf16 x, y, z, w; };
typedef __attribute__((ext_vector_type(8))) short short8;
typedef __attribute__((ext_vector_type(4))) float float4v;

__device__ inline float b2f(bf16 v) { return __bfloat162float(v); }
__device__ inline bf16 f2b(float v) { return __float2bfloat16(v); }
__device__ inline unsigned short f2bu(float f) {
    bf16 b = __float2bfloat16(f); unsigned short u; __builtin_memcpy(&u, &b, 2); return u;
}

// async global->LDS, 16 bytes per lane; LDS dest = uniform base + lane*16
typedef const unsigned int __attribute__((address_space(1)))* gas_t;
typedef unsigned int __attribute__((address_space(3)))* las_t;
__device__ __forceinline__ void gl_lds16(const unsigned short* g, unsigned short* l) {
    __builtin_amdgcn_global_load_lds((gas_t)g, (las_t)l, 16, 0, 0);
}

// ---------------- small utility ----------------

__global__ void k_zero_f(float* __restrict__ p, int n) {
    int i = blockIdx.x * blockDim.x + threadIdx.x;
    if (i < n) p[i] = 0.f;
}
__global__ void k_zero_i(int* __restrict__ p, int n) {
    int i = blockIdx.x * blockDim.x + threadIdx.x;
    if (i < n) p[i] = 0;
}

// ---------------- weight split: W[K][N] f32 -> Wt_hi/lo[Npad][Kpad] bf16 ----------------

__global__ void k_split(const float* __restrict__ W, int K, int N, int Kpad, int Npad,
                        unsigned short* __restrict__ hi, unsigned short* __restrict__ lo) {
    int idx = blockIdx.x * blockDim.x + threadIdx.x;
    if (idx >= Npad * Kpad) return;
    int n = idx / Kpad, k = idx % Kpad;
    float v = (n < N && k < K) ? W[(size_t)k * N + n] : 0.f;
    bf16 h = __float2bfloat16(v);
    float rem = v - __bfloat162float(h);
    bf16 l = __float2bfloat16(rem);
    unsigned short hu, lu;
    __builtin_memcpy(&hu, &h, 2); __builtin_memcpy(&lu, &l, 2);
    hi[idx] = hu; lo[idx] = lu;
}

// f[G,300] f32 -> hi/lo [G,320] bf16 (pad zero)
__global__ void k_fsplit(const float* __restrict__ f, unsigned short* __restrict__ hi,
                         unsigned short* __restrict__ lo, int G) {
    int idx = blockIdx.x * blockDim.x + threadIdx.x;
    if (idx >= G * AGGP) return;
    int g = idx / AGGP, c = idx % AGGP;
    float v = (c < EMB) ? f[(size_t)g * EMB + c] : 0.f;
    bf16 h = __float2bfloat16(v);
    float rem = v - __bfloat162float(h);
    unsigned short hu; __builtin_memcpy(&hu, &h, 2);
    hi[idx] = hu;
    lo[idx] = f2bu(rem);
}

// ---------------- CSR build (dst-sorted edge ids) ----------------

__global__ void k_hist(const int* __restrict__ ei, int* __restrict__ deg, int E) {
    int e = blockIdx.x * blockDim.x + threadIdx.x;
    if (e < E) atomicAdd(&deg[ei[E + e]], 1);
}

__global__ void k_chunksum(const int* __restrict__ deg, int* __restrict__ csum, int total) {
    __shared__ int s[256];
    int t = threadIdx.x, i = blockIdx.x * 256 + t;
    s[t] = (i < total) ? deg[i] : 0;
    __syncthreads();
    for (int off = 128; off > 0; off >>= 1) {
        if (t < off) s[t] += s[t + off];
        __syncthreads();
    }
    if (t == 0) csum[blockIdx.x] = s[0];
}

__global__ void k_scanchunks(const int* __restrict__ csum, int* __restrict__ coff, int n) {
    if (threadIdx.x == 0) {
        int acc = 0;
        for (int b = 0; b < n; ++b) { coff[b] = acc; acc += csum[b]; }
    }
}

__global__ void k_scan2(const int* __restrict__ deg, const int* __restrict__ coff,
                        int* __restrict__ rowstart, int total) {
    __shared__ int s[256];
    int t = threadIdx.x, b = blockIdx.x, i = b * 256 + t;
    int v = (i < total) ? deg[i] : 0;
    s[t] = v;
    __syncthreads();
    for (int off = 1; off < 256; off <<= 1) {
        int u = (t >= off) ? s[t - off] : 0;
        __syncthreads();
        s[t] += u;
        __syncthreads();
    }
    if (i < total) rowstart[i] = coff[b] + s[t] - v;
}

__global__ void k_initcursor(const int* __restrict__ rowstart, int* __restrict__ cur, int N) {
    int i = blockIdx.x * blockDim.x + threadIdx.x;
    if (i < N) cur[i] = rowstart[i];
}

__global__ void k_fill(const int* __restrict__ ei, int* __restrict__ cur,
                       int* __restrict__ esorted, int E) {
    int e = blockIdx.x * blockDim.x + threadIdx.x;
    if (e < E) {
        int p = atomicAdd(&cur[ei[E + e]], 1);
        esorted[p] = e;
    }
}

// packed[p] = src | (combo<<17), combo = a0*3+a1 (18 combos; self-loop=12)
__global__ void k_pack(const int* __restrict__ ei, const int* __restrict__ ea,
                       const int* __restrict__ esorted, int* __restrict__ packed, int E) {
    int p = blockIdx.x * blockDim.x + threadIdx.x;
    if (p >= E) return;
    int e = esorted[p];
    int s = ei[e];
    int cb = ea[2 * e] * 3 + ea[2 * e + 1];
    packed[p] = s | (cb << 17);
}

// canonical per-bucket order: insertion-sort packed values within each node's
// CSR range -> deterministic fp32 aggregation sum order across calls.
__global__ void k_sortb(const int* __restrict__ rowstart, int* __restrict__ packed, int N) {
    int n = blockIdx.x * blockDim.x + threadIdx.x;
    if (n >= N) return;
    int p0 = rowstart[n], p1 = rowstart[n + 1];
    for (int i = p0 + 1; i < p1; ++i) {
        int v = packed[i];
        int j = i - 1;
        while (j >= p0 && packed[j] > v) { packed[j + 1] = packed[j]; --j; }
        packed[j + 1] = v;
    }
}

__global__ void k_gstart(const int* __restrict__ batch, int* __restrict__ gstart, int N) {
    int g = blockIdx.x * blockDim.x + threadIdx.x;
    if (g > NGRAPH) return;
    int lo = 0, hi = N;
    while (lo < hi) { int mid = (lo + hi) >> 1; if (batch[mid] < g) lo = mid + 1; else hi = mid; }
    gstart[g] = lo;
}

// per-layer combo table: cmb[cb][300] = e1[cb/3] + e2[cb%3]  (fp32)
__global__ void k_combo(const float4* __restrict__ e1, const float4* __restrict__ e2,
                        float4* __restrict__ cmb) {
    int t = blockIdx.x * blockDim.x + threadIdx.x;
    if (t >= 18 * EMBC) return;
    int cb = t / EMBC, j = t % EMBC;
    float4 u = e1[(cb / 3) * EMBC + j];
    float4 v = e2[(cb % 3) * EMBC + j];
    float4 r; r.x = u.x + v.x; r.y = u.y + v.y; r.z = u.z + v.z; r.w = u.w + v.w;
    cmb[t] = r;
}

// ---------------- node init & aggregation (with fused BN affine) ----------------

__global__ void k_init_h(const int* __restrict__ x,
                         const float4* __restrict__ ae1,
                         const float4* __restrict__ ae2,
                         bf4* __restrict__ h4, int N) {
    int idx = blockIdx.x * blockDim.x + threadIdx.x;
    if (idx >= N * EMBC) return;
    int i = idx / EMBC, j = idx % EMBC;
    int a0 = x[2 * i], a1 = x[2 * i + 1];
    float4 u = ae1[a0 * EMBC + j];
    float4 v = ae2[a1 * EMBC + j];
    bf4 r = { f2b(u.x + v.x), f2b(u.y + v.y), f2b(u.z + v.z), f2b(u.w + v.w) };
    h4[idx] = r;
}

// agg[n] = act(h[n]) + cmb[12] + sum_p ( act(h[src(p)]) + cmb[combo(p)] )
__global__ void k_aggregate(const bf4* __restrict__ h4,
                            const int* __restrict__ packed,
                            const float4* __restrict__ cmb,   // [18,75]
                            const int* __restrict__ rowstart,
                            const float* __restrict__ stats, int use_aff,
                            bf4* __restrict__ agg4, int N) {
    int idx = blockIdx.x * blockDim.x + threadIdx.x;
    if (idx >= N * AGGC) return;
    int n = idx / AGGC, j = idx % AGGC;
    if (j >= EMBC) {
        bf4 z = { f2b(0.f), f2b(0.f), f2b(0.f), f2b(0.f) };
        agg4[idx] = z;
        return;
    }
    float4 sc = make_float4(1.f, 1.f, 1.f, 1.f);
    float4 sh = make_float4(0.f, 0.f, 0.f, 0.f);
    if (use_aff) {
        sc = ((const float4*)stats)[j];
        sh = ((const float4*)(stats + EMB))[j];
    }
    bf4 hv = h4[(size_t)n * EMBC + j];
    float hx = b2f(hv.x), hy = b2f(hv.y), hz = b2f(hv.z), hw = b2f(hv.w);
    if (use_aff) {
        hx = fmaxf(hx * sc.x + sh.x, 0.f); hy = fmaxf(hy * sc.y + sh.y, 0.f);
        hz = fmaxf(hz * sc.z + sh.z, 0.f); hw = fmaxf(hw * sc.w + sh.w, 0.f);
    }
    float4 s0 = cmb[12 * EMBC + j];      // self-loop combo (edge_attr [4,0])
    float ax = hx + s0.x, ay = hy + s0.y, az = hz + s0.z, aw = hw + s0.w;
    int p0 = rowstart[n], p1 = rowstart[n + 1];
    for (int p = p0; p < p1; ++p) {
        int u = packed[p];
        int s = u & 131071;
        int cb = u >> 17;
        bf4 hs = h4[(size_t)s * EMBC + j];
        float gx = b2f(hs.x), gy = b2f(hs.y), gz = b2f(hs.z), gw = b2f(hs.w);
        if (use_aff) {
            gx = fmaxf(gx * sc.x + sh.x, 0.f); gy = fmaxf(gy * sc.y + sh.y, 0.f);
            gz = fmaxf(gz * sc.z + sh.z, 0.f); gw = fmaxf(gw * sc.w + sh.w, 0.f);
        }
        float4 cv = cmb[cb * EMBC + j];
        ax += gx + cv.x; ay += gy + cv.y;
        az += gz + cv.z; aw += gw + cv.w;
    }
    bf4 r = { f2b(ax), f2b(ay), f2b(az), f2b(aw) };
    agg4[idx] = r;
}

// BN(h) copy for projector: dst[N,320] = scale*h + shift (no relu), pad zeroed
__global__ void k_bncopy(const bf4* __restrict__ h4, const float* __restrict__ stats,
                         bf4* __restrict__ dst, int N) {
    int idx = blockIdx.x * blockDim.x + threadIdx.x;
    if (idx >= N * AGGC) return;
    int n = idx / AGGC, j = idx % AGGC;
    if (j >= EMBC) {
        bf4 z = { f2b(0.f), f2b(0.f), f2b(0.f), f2b(0.f) };
        dst[idx] = z;
        return;
    }
    float4 sc = ((const float4*)stats)[j];
    float4 sh = ((const float4*)(stats + EMB))[j];
    bf4 v = h4[(size_t)n * EMBC + j];
    bf4 r = { f2b(b2f(v.x) * sc.x + sh.x), f2b(b2f(v.y) * sc.y + sh.y),
              f2b(b2f(v.z) * sc.z + sh.z), f2b(b2f(v.w) * sc.w + sh.w) };
    dst[idx] = r;
}

// ---------------- MFMA GEMM: C_bf16[M,Nc] = A_bf16[M,K] @ (Bhi+Blo)^T + bias --------
// Round 13: tile 128x64, GBK=32. A: LDS double-buffer (16 KB), staged via
// global_load_lds, plain __syncthreads 2-phase (R9==R10 proved sync flavor
// irrelevant). B: hi/lo fragments read DIRECTLY from global (L2-resident
// weights) into registers, prefetched one K-step ahead (bc/bn register
// pairs, explicit names — no runtime-indexed arrays). Fragment bytes and
// MFMA order identical to the staged path => bit-identical output.
// 4 waves in 2x2 grid of 64x32 tiles (acc[4][2]).

#define GBM 128
#define GBN 64
#define GBK 32

__global__ __launch_bounds__(256, 4)
void k_gemm_mfma(const unsigned short* __restrict__ A, int lda, int Kpad,
                 const unsigned short* __restrict__ Bhi,
                 const unsigned short* __restrict__ Blo, int ldb,
                 const float* __restrict__ bias,
                 unsigned short* __restrict__ C, int ldc, int M, int Nc, int relu,
                 float* __restrict__ psum, int do_stats) {
    __shared__ unsigned short As[2][GBM][GBK];   // 16 KB (reused as cred)

    int tid = threadIdx.x;
    int wv = tid >> 6, lane = tid & 63;
    int quad = lane >> 4, l16 = lane & 15;
    int wm = wv & 1, wn = wv >> 1;            // 2x2 wave grid of 64x32 tiles

    // A staging lane mapping: 4 lanes/row, chunk XOR-swizzled by row pair
    int srow = lane >> 2;                     // 0..15
    int gch = (lane & 3) ^ ((lane >> 3) & 3); // global 8-elem chunk
    // A read swizzle
    int pc = quad ^ ((l16 >> 1) & 3);

    // XCD swizzle: col-tiles of one row-block get linear ids equal mod 8
    int ncols = gridDim.x, nrows = gridDim.y;
    int lin = blockIdx.y * ncols + blockIdx.x;
    int g = lin / (8 * ncols);
    int rem = lin - g * 8 * ncols;
    int rows_in = min(8, nrows - g * 8);
    int colb = rem / rows_in;
    int rowb = g * 8 + (rem - colb * rows_in);
    int row0 = rowb * GBM;
    int col0 = colb * GBN;

    // A staging source bases: wave wv stages rows [32wv,32wv+32)
    const unsigned short* Asrc0;
    const unsigned short* Asrc1;
    {
        int r0 = 32 * wv + srow;
        int r1 = 32 * wv + 16 + srow;
        Asrc0 = A + (size_t)min(row0 + r0, M - 1) * lda + gch * 8;
        Asrc1 = A + (size_t)min(row0 + r1, M - 1) * lda + gch * 8;
    }
    // B direct per-lane fragment pointers: lane reads B[col][quad*8 + k .. +8]
    const unsigned short* Bp0 = Bhi + (size_t)(col0 + 32 * wn + l16) * ldb + quad * 8;
    const unsigned short* Bp1 = Bhi + (size_t)(col0 + 32 * wn + 16 + l16) * ldb + quad * 8;
    const size_t dBL = (size_t)(Blo - Bhi);

    float4v acc[4][2];
    #pragma unroll
    for (int i = 0; i < 4; ++i)
        #pragma unroll
        for (int j = 0; j < 2; ++j) acc[i][j] = (float4v){0.f, 0.f, 0.f, 0.f};

    const int ntk = Kpad / GBK;

    // prologue: stage A tile 0; load B fragments for step 0
    gl_lds16(Asrc0, &As[0][32 * wv][0]);
    gl_lds16(Asrc1, &As[0][32 * wv + 16][0]);
    short8 bc0 = *(const short8*)(Bp0);
    short8 bc1 = *(const short8*)(Bp0 + dBL);
    short8 bc2 = *(const short8*)(Bp1);
    short8 bc3 = *(const short8*)(Bp1 + dBL);
    __syncthreads();

    for (int t = 0; t < ntk; ++t) {
        int cur = t & 1;
        // prefetch next step: A tile into buf^1, B frags into regs
        short8 bn0, bn1, bn2, bn3;
        if (t + 1 < ntk) {
            int k1 = (t + 1) * GBK;
            gl_lds16(Asrc0 + k1, &As[cur ^ 1][32 * wv][0]);
            gl_lds16(Asrc1 + k1, &As[cur ^ 1][32 * wv + 16][0]);
            bn0 = *(const short8*)(Bp0 + k1);
            bn1 = *(const short8*)(Bp0 + k1 + dBL);
            bn2 = *(const short8*)(Bp1 + k1);
            bn3 = *(const short8*)(Bp1 + k1 + dBL);
        }
        // compute current tile: wave (wm,wn) rows [64wm..+64) x cols [32wn..+32)
        short8 a[4];
        #pragma unroll
        for (int mt = 0; mt < 4; ++mt)
            a[mt] = *(const short8*)(&As[cur][64 * wm + mt * 16 + l16][pc * 8]);
        #pragma unroll
        for (int mt = 0; mt < 4; ++mt) {
            acc[mt][0] = __builtin_amdgcn_mfma_f32_16x16x32_bf16(a[mt], bc0, acc[mt][0], 0, 0, 0);
            acc[mt][0] = __builtin_amdgcn_mfma_f32_16x16x32_bf16(a[mt], bc1, acc[mt][0], 0, 0, 0);
        }
        #pragma unroll
        for (int mt = 0; mt < 4; ++mt) {
            acc[mt][1] = __builtin_amdgcn_mfma_f32_16x16x32_bf16(a[mt], bc2, acc[mt][1], 0, 0, 0);
            acc[mt][1] = __builtin_amdgcn_mfma_f32_16x16x32_bf16(a[mt], bc3, acc[mt][1], 0, 0, 0);
        }
        __syncthreads();   // drains A staging + B prefetch; buf swap safe
        bc0 = bn0; bc1 = bn1; bc2 = bn2; bc3 = bn3;
    }

    // epilogue: C/D layout col=lane&15, row=quad*4+reg
    float sv[2], qv[2];
    #pragma unroll
    for (int ntl = 0; ntl < 2; ++ntl) { sv[ntl] = 0.f; qv[ntl] = 0.f; }
    #pragma unroll
    for (int mt = 0; mt < 4; ++mt) {
        int rbase = row0 + 64 * wm + mt * 16 + quad * 4;
        #pragma unroll
        for (int ntl = 0; ntl < 2; ++ntl) {
            int c = col0 + 32 * wn + ntl * 16 + l16;
            if (c >= Nc) continue;
            float bs = bias[c];
            #pragma unroll
            for (int i = 0; i < 4; ++i) {
                int r = rbase + i;
                if (r >= M) continue;
                float v = acc[mt][ntl][i] + bs;
                if (relu) v = fmaxf(v, 0.f);
                if (do_stats) { sv[ntl] += v; qv[ntl] += v * v; }
                C[(size_t)r * ldc + c] = f2bu(v);
            }
        }
    }
    if (do_stats) {
        float* cred = (float*)(&As[0][0][0]);   // 4 waves x 32 s + 4 waves x 32 q
        #pragma unroll
        for (int ntl = 0; ntl < 2; ++ntl) {
            float s = sv[ntl], q = qv[ntl];
            s += __shfl_down(s, 32, 64); s += __shfl_down(s, 16, 64);
            q += __shfl_down(q, 32, 64); q += __shfl_down(q, 16, 64);
            if (quad == 0) {
                cred[wv * 64 + ntl * 16 + l16] = s;
                cred[256 + wv * 64 + ntl * 16 + l16] = q;
            }
        }
        __syncthreads();
        if (tid < 64) {
            // per-row-block partial: psum[rowb][c] = s, psum[rowb][384+c] = q
            // col group g = tid>>5 (wn), waves wv = 2g (rows 0-63) then 2g+1
            int gc = tid >> 5, cin = tid & 31;
            float s = cred[(2 * gc) * 64 + cin] + cred[(2 * gc + 1) * 64 + cin];
            float q = cred[256 + (2 * gc) * 64 + cin] + cred[256 + (2 * gc + 1) * 64 + cin];
            int c = col0 + tid;
            psum[(size_t)rowb * 768 + c] = s;
            psum[(size_t)rowb * 768 + 384 + c] = q;
        }
    }
}

// ---------------- logits MFMA: out = scale * (Ah+Al) @ (Bh+Bl)^T  (ll skipped) ----

__global__ __launch_bounds__(256)
void k_logits(const unsigned short* __restrict__ Ahg, const unsigned short* __restrict__ Alg,
              const unsigned short* __restrict__ Bhg, const unsigned short* __restrict__ Blg,
              float* __restrict__ C, float scale) {
    __shared__ unsigned short sAh[64][64];
    __shared__ unsigned short sAl[64][64];
    __shared__ unsigned short sBh[128][64];
    __shared__ unsigned short sBl[128][64];

    int tid = threadIdx.x;
    int wv = tid >> 6, lane = tid & 63;
    int quad = lane >> 4, l16 = lane & 15;
    int lrow = lane >> 3;
    int gchunk = (lane & 7) ^ lrow;
    int sw = lane & 7;
    int row0 = blockIdx.y * 64;
    int col0 = blockIdx.x * 128;

    float4v acc[8];
    #pragma unroll
    for (int j = 0; j < 8; ++j) acc[j] = (float4v){0.f, 0.f, 0.f, 0.f};

    for (int k0 = 0; k0 < AGGP; k0 += 64) {
        #pragma unroll
        for (int j = 0; j < 2; ++j) {
            int r = 16 * wv + 8 * j + lrow;
            size_t go = (size_t)(row0 + r) * AGGP + k0 + gchunk * 8;
            gl_lds16(Ahg + go, &sAh[16 * wv + 8 * j][0]);
            gl_lds16(Alg + go, &sAl[16 * wv + 8 * j][0]);
        }
        #pragma unroll
        for (int j = 0; j < 4; ++j) {
            int r = 32 * wv + 8 * j + lrow;
            size_t go = (size_t)(col0 + r) * AGGP + k0 + gchunk * 8;
            gl_lds16(Bhg + go, &sBh[32 * wv + 8 * j][0]);
            gl_lds16(Blg + go, &sBl[32 * wv + 8 * j][0]);
        }
        __syncthreads();

        #pragma unroll
        for (int ks = 0; ks < 64; ks += 32) {
            int pcl = ((ks >> 3) + quad) ^ sw;
            short8 ah = *(const short8*)(&sAh[wv * 16 + l16][pcl * 8]);
            short8 al = *(const short8*)(&sAl[wv * 16 + l16][pcl * 8]);
            #pragma unroll
            for (int nt = 0; nt < 8; ++nt) {
                short8 bh = *(const short8*)(&sBh[nt * 16 + l16][pcl * 8]);
                short8 bl = *(const short8*)(&sBl[nt * 16 + l16][pcl * 8]);
                acc[nt] = __builtin_amdgcn_mfma_f32_16x16x32_bf16(ah, bh, acc[nt], 0, 0, 0);
                acc[nt] = __builtin_amdgcn_mfma_f32_16x16x32_bf16(ah, bl, acc[nt], 0, 0, 0);
                acc[nt] = __builtin_amdgcn_mfma_f32_16x16x32_bf16(al, bh, acc[nt], 0, 0, 0);
            }
        }
        __syncthreads();
    }

    int rbase = row0 + wv * 16 + quad * 4;
    #pragma unroll
    for (int nt = 0; nt < 8; ++nt) {
        int c = col0 + nt * 16 + l16;
        #pragma unroll
        for (int i = 0; i < 4; ++i)
            C[(size_t)(rbase + i) * NGRAPH + c] = acc[nt][i] * scale;
    }
}

// ---------------- BN stats reduction (deterministic, two-stage) ----------------

__global__ void k_statred(const float* __restrict__ psum, float* __restrict__ part2, int nrb) {
    int b = blockIdx.x, c = threadIdx.x;   // 768 threads
    float acc = 0.f;
    for (int r = b; r < nrb; r += NRED) acc += psum[(size_t)r * 768 + c];
    part2[b * 768 + c] = acc;
}

__global__ void k_bn_prep(const float* __restrict__ part2, float* __restrict__ stats,
                          const float* __restrict__ gamma, const float* __restrict__ beta,
                          float invN) {
    int c = threadIdx.x;
    if (c >= EMB) return;
    float s = 0.f, q = 0.f;
    for (int b = 0; b < NRED; ++b) {
        s += part2[b * 768 + c];
        q += part2[b * 768 + 384 + c];
    }
    float mean = s * invN;
    float var = q * invN - mean * mean;
    float scale = gamma[c] * rsqrtf(var + BN_EPS);
    stats[c] = scale;
    stats[EMB + c] = beta[c] - mean * scale;
}

// ---------------- fused pool + mean + L2 normalize (proj pitch 320) ----------------

__global__ void k_poolnorm(const bf16* __restrict__ proj, const int* __restrict__ gstart,
                           float* __restrict__ f) {
    int g = blockIdx.x, t = threadIdx.x;
    int s = gstart[g], e = gstart[g + 1];
    float sum = 0.f;
    if (t < EMB)
        for (int r = s; r < e; ++r) sum += b2f(proj[(size_t)r * AGGP + t]);
    float cnt = fmaxf((float)(e - s), 1.f);
    float m = sum / cnt;
    float q = (t < EMB) ? m * m : 0.f;
    for (int off = 32; off > 0; off >>= 1) q += __shfl_down(q, off, 64);
    __shared__ float red[5];
    int lane = t & 63, wid = t >> 6;
    if (lane == 0) red[wid] = q;
    __syncthreads();
    float tot = red[0] + red[1] + red[2] + red[3] + red[4];
    float invn = 1.f / fmaxf(sqrtf(tot), 1e-12f);
    if (t < EMB) f[(size_t)g * EMB + t] = m * invn;
}

// ---------------- host ----------------

static inline int ceil_div(int a, int b) { return (a + b - 1) / b; }

extern "C" void kernel_launch(void* const* d_in, const int* in_sizes, int n_in,
                              void* d_out, int out_size, void* d_ws, size_t ws_size,
                              hipStream_t stream) {
    const int N = in_sizes[0] / 2;    // 100000
    const int E = in_sizes[1] / 2;    // 400000

    const int* x[2]  = { (const int*)d_in[0], (const int*)d_in[4] };
    const int* ei[2] = { (const int*)d_in[1], (const int*)d_in[5] };
    const int* ea[2] = { (const int*)d_in[2], (const int*)d_in[6] };
    const int* bt[2] = { (const int*)d_in[3], (const int*)d_in[7] };
    const float* atom1 = (const float*)d_in[8];
    const float* atom2 = (const float*)d_in[9];
    const float* ee1 = (const float*)d_in[10];   // [5,6,300]
    const float* ee2 = (const float*)d_in[11];   // [5,3,300]
    const float* w1  = (const float*)d_in[12];   // [5,300,600]
    const float* b1  = (const float*)d_in[13];   // [5,600]
    const float* w2  = (const float*)d_in[14];   // [5,600,300]
    const float* b2  = (const float*)d_in[15];   // [5,300]
    const float* gam = (const float*)d_in[16];
    const float* bet = (const float*)d_in[17];
    const float* pw  = (const float*)d_in[18];   // [300,300]
    const float* pb  = (const float*)d_in[19];
    float* out = (float*)d_out;

    // ---- workspace ----
    char* wsb = (char*)d_ws;
    bf16* h    = (bf16*)(wsb);
    bf16* agg  = (bf16*)(wsb + 60000000);
    bf16* hid  = (bf16*)(wsb + 124000000);
    float* guard = (float*)(wsb + 244000000);    // 64 floats, zeroed
    float* f0  = (float*)(wsb + 244000256);
    float* f1  = (float*)(wsb + 248915456);
    // f-splits for logits reuse the (dead) hid region
    unsigned short* f0hi = (unsigned short*)(wsb + 124000000);
    unsigned short* f0lo = (unsigned short*)(wsb + 126621440);
    unsigned short* f1hi = (unsigned short*)(wsb + 129242880);
    unsigned short* f1lo = (unsigned short*)(wsb + 131864320);

    // ---- d_out scratch (consumed before logits GEMM) ----
    int* deg      = (int*)d_out;              // N+1
    int* rowstart = deg + (N + 1);            // N+1
    int* cursor   = rowstart + (N + 1);       // N
    int* esorted  = cursor + N;               // E
    int* packed   = esorted + E;              // E
    int* csum     = packed + E;               // 512
    int* coff     = csum + 512;               // 512
    int* gstart   = coff + 512;               // 4097
    float* stats  = (float*)(gstart + 4097);  // 600
    float* cmb    = stats + 600;              // 18*300
    char* splits  = (char*)d_out + 4500224;   // 256B-aligned
    unsigned short* w1hi = (unsigned short*)(splits);               // 5*[640][320]
    unsigned short* w1lo = (unsigned short*)(splits + 2048000);
    unsigned short* w2hi = (unsigned short*)(splits + 4096000);     // 5*[384][640]
    unsigned short* w2lo = (unsigned short*)(splits + 6553600);
    unsigned short* pjhi = (unsigned short*)(splits + 9011200);     // [384][320]
    unsigned short* pjlo = (unsigned short*)(splits + 9256960);
    float* psum  = (float*)((char*)d_out + 20971520);               // [782][768]
    float* part2 = (float*)((char*)d_out + 25165824);               // [NRED][768]

    const int TB = 256;
    const int nh_blocks = ceil_div(N * EMBC, TB);
    const int na_blocks = ceil_div(N * AGGC, TB);
    const int nchunks = ceil_div(N + 1, 256);
    const float invN = 1.f / (float)N;

    // zero the guard after hid (GEMM2 last-row K-overrun lands here)
    k_zero_f<<<1, 64, 0, stream>>>(guard, 64);

    // ---- split all weights (once; shared by both branches) ----
    for (int l = 0; l < 5; ++l) {
        k_split<<<ceil_div(640 * 320, TB), TB, 0, stream>>>(
            w1 + (size_t)l * EMB * HID, EMB, HID, 320, 640,
            w1hi + (size_t)l * 640 * 320, w1lo + (size_t)l * 640 * 320);
        k_split<<<ceil_div(384 * 640, TB), TB, 0, stream>>>(
            w2 + (size_t)l * HID * EMB, HID, EMB, 640, 384,
            w2hi + (size_t)l * 384 * 640, w2lo + (size_t)l * 384 * 640);
    }
    k_split<<<ceil_div(384 * 320, TB), TB, 0, stream>>>(pw, EMB, EMB, 320, 384, pjhi, pjlo);

    const int mrows = ceil_div(N, GBM);       // 782
    dim3 g1(10, mrows);   // GEMM1: Npad=640, 64-col tiles
    dim3 g2(6, mrows);    // GEMM2/proj: Npad=384
    dim3 glg(32, 64);     // logits

    for (int br = 0; br < 2; ++br) {
        float* fout = br == 0 ? f0 : f1;
        // ---- CSR build + packed edges (canonical per-bucket order) ----
        k_zero_i<<<ceil_div(N + 1, TB), TB, 0, stream>>>(deg, N + 1);
        k_hist<<<ceil_div(E, TB), TB, 0, stream>>>(ei[br], deg, E);
        k_chunksum<<<nchunks, 256, 0, stream>>>(deg, csum, N + 1);
        k_scanchunks<<<1, 64, 0, stream>>>(csum, coff, nchunks);
        k_scan2<<<nchunks, 256, 0, stream>>>(deg, coff, rowstart, N + 1);
        k_initcursor<<<ceil_div(N, TB), TB, 0, stream>>>(rowstart, cursor, N);
        k_fill<<<ceil_div(E, TB), TB, 0, stream>>>(ei[br], cursor, esorted, E);
        k_pack<<<ceil_div(E, TB), TB, 0, stream>>>(ei[br], ea[br], esorted, packed, E);
        k_sortb<<<ceil_div(N, TB), TB, 0, stream>>>(rowstart, packed, N);
        k_gstart<<<ceil_div(NGRAPH + 1, TB), TB, 0, stream>>>(bt[br], gstart, N);
        // ---- encoder ----
        k_init_h<<<nh_blocks, TB, 0, stream>>>(x[br], (const float4*)atom1,
                                               (const float4*)atom2, (bf4*)h, N);
        for (int l = 0; l < 5; ++l) {
            k_combo<<<ceil_div(18 * EMBC, TB), TB, 0, stream>>>(
                (const float4*)(ee1 + (size_t)l * 6 * EMB),
                (const float4*)(ee2 + (size_t)l * 3 * EMB), (float4*)cmb);
            k_aggregate<<<na_blocks, TB, 0, stream>>>((const bf4*)h, packed,
                                                      (const float4*)cmb, rowstart,
                                                      stats, l > 0, (bf4*)agg, N);
            // GEMM1: [N,320] @ [640,320]^T -> hid [N,600]
            k_gemm_mfma<<<g1, 256, 0, stream>>>(
                (const unsigned short*)agg, AGGP, AGGP,
                w1hi + (size_t)l * 640 * 320, w1lo + (size_t)l * 640 * 320, 320,
                b1 + (size_t)l * HID, (unsigned short*)hid, HID, N, HID, 1,
                nullptr, 0);
            // GEMM2: K 600..639 reads garbage x zero weights = 0
            k_gemm_mfma<<<g2, 256, 0, stream>>>(
                (const unsigned short*)hid, HID, 640,
                w2hi + (size_t)l * 384 * 640, w2lo + (size_t)l * 384 * 640, 640,
                b2 + (size_t)l * EMB, (unsigned short*)h, EMB, N, EMB, 0,
                psum, 1);
            k_statred<<<NRED, 768, 0, stream>>>(psum, part2, mrows);
            k_bn_prep<<<1, 320, 0, stream>>>(part2, stats, gam + (size_t)l * EMB,
                                             bet + (size_t)l * EMB, invN);
        }
        // BN(h) copy (pitch 320, zero-padded) into hid buffer for projector
        k_bncopy<<<na_blocks, TB, 0, stream>>>((const bf4*)h, stats, (bf4*)hid, N);
        // projector: [N,320] @ [384,320]^T -> agg (pitch 320)
        k_gemm_mfma<<<g2, 256, 0, stream>>>(
            (const unsigned short*)hid, AGGP, AGGP,
            pjhi, pjlo, 320, pb, (unsigned short*)agg, AGGP, N, EMB, 0,
            nullptr, 0);
        // fused pool + mean + L2 norm
        k_poolnorm<<<NGRAPH, 320, 0, stream>>>(agg, gstart, fout);
    }
    // ---- logits: split f0/f1 (hid region now dead), 3-pass MFMA ----
    k_fsplit<<<ceil_div(NGRAPH * AGGP, TB), TB, 0, stream>>>(f0, f0hi, f0lo, NGRAPH);
    k_fsplit<<<ceil_div(NGRAPH * AGGP, TB), TB, 0, stream>>>(f1, f1hi, f1lo, NGRAPH);
    k_logits<<<glg, 256, 0, stream>>>(f0hi, f0lo, f1hi, f1lo, out, INV_TEMP);
}

// Round 9
// 4627.726 us; speedup vs baseline: 1.3729x; 1.3729x over previous
//
#include <hip/hip_runtime.h>
#include <hip/hip_bf16.h>

// 5-layer GNN encoder x2 branches + projector + mean-pool + L2norm + logits.
// Round 15 = Round 14 resubmit (bench infra failed twice; no kernel verdict).
// FRAGMENT-MAJOR GEMM — no LDS, no barriers. History: barriers/vmcnt null
// (R9/R10), occupancy>3blk null (R12), fat tile −57% (R11), per-lane direct
// loads regress as gathers (R7 A-side, R13 B-side). Fix the mechanism: store
// operands in fragment order FA[rowtile][kstep][lane][8] so a wave's MFMA
// fragment = base + lane*16B — one coalesced 1KB load to registers. B
// permuted in k_split; A written fragment-major by producers (k_aggregate,
// GEMM1 epilogue, k_bncopy). GEMM K-loop: 8 coalesced loads + 16 MFMA per
// step, 1-deep register prefetch, zero LDS traffic, zero barriers. Fragment
// bytes + per-accumulator (hi,lo,k) order identical to the verified LDS path
// => bit-identical output (absmax 0.421875). GEMM1 writes ALL 640 hid cols
// (0 beyond 600) so GEMM2 reads only freshly-written bytes each layer.
// Determinism machinery kept (fixed-slot BN psum + two-stage reduce,
// canonical CSR bucket sort).
//
// d_ws layout (bytes):
//   h     bf16 linear [N,300]      @ 0           (GEMM2 C; read by aggregate/bncopy)
//   aggf  bf16 frag [6250][10]     @ 60,000,000  (GEMM1 A; later bncopy-out = proj A)
//   hidf  bf16 frag [6250][20]     @ 124,000,000 (GEMM1 C / GEMM2 A; later proj C
//                                                 linear [N,320] + f-splits; 128MB)
// d_out doubles as scratch: CSR + stats + combo + split weights + psum/part2
// + f0/f1 (@33.5MB/@38.5MB) — all consumed before the final logits GEMM.

#define EMB 300
#define EMBC 75       // 300/4 chunks (h pitch 300)
#define AGGP 320      // padded K of agg/proj operands
#define AGGC 80
#define HID 600
#define NGRAPH 4096
#define BN_EPS 1e-5f
#define INV_TEMP 25.0f
#define NRED 24       // stage-1 stat-reduction blocks

typedef __hip_bfloat16 bf16;
struct __align__(8) bf4 { bf16 x, y, z, w; };
typedef __attribute__((ext_vector_type(8))) short short8;
typedef __attribute__((ext_vector_type(4))) float float4v;

__device__ inline float b2f(bf16 v) { return __bfloat162float(v); }
__device__ inline bf16 f2b(float v) { return __float2bfloat16(v); }
__device__ inline unsigned short f2bu(float f) {
    bf16 b = __float2bfloat16(f); unsigned short u; __builtin_memcpy(&u, &b, 2); return u;
}

// fragment-major offset: element (row,k) of a [rows][Kpad] matrix lives at
// tile (row>>4, k>>5), lane (row&15)+16*((k>>3)&3), elem k&7.
// A wave's fragment for (rowtile rt, kstep ks) is then 64 lanes x 16B
// contiguous at ((rt*nks+ks)<<9): perfectly coalesced.
__device__ inline size_t foff(int row, int k, int nks) {
    return (((size_t)((row >> 4) * nks + (k >> 5))) << 9)
         + (((row & 15) + 16 * ((k >> 3) & 3)) << 3) + (k & 7);
}

// async global->LDS (still used by k_logits only)
typedef const unsigned int __attribute__((address_space(1)))* gas_t;
typedef unsigned int __attribute__((address_space(3)))* las_t;
__device__ __forceinline__ void gl_lds16(const unsigned short* g, unsigned short* l) {
    __builtin_amdgcn_global_load_lds((gas_t)g, (las_t)l, 16, 0, 0);
}

// ---------------- small utility ----------------

__global__ void k_zero_i(int* __restrict__ p, int n) {
    int i = blockIdx.x * blockDim.x + threadIdx.x;
    if (i < n) p[i] = 0;
}

// ---------------- weight split: W[K][N] f32 -> fragment-major hi/lo bf16 --------

__global__ void k_split(const float* __restrict__ W, int K, int N, int Kpad, int Npad,
                        unsigned short* __restrict__ hi, unsigned short* __restrict__ lo) {
    int idx = blockIdx.x * blockDim.x + threadIdx.x;
    if (idx >= Npad * Kpad) return;
    int n = idx / Kpad, k = idx % Kpad;
    float v = (n < N && k < K) ? W[(size_t)k * N + n] : 0.f;
    bf16 h = __float2bfloat16(v);
    float rem = v - __bfloat162float(h);
    bf16 l = __float2bfloat16(rem);
    unsigned short hu, lu;
    __builtin_memcpy(&hu, &h, 2); __builtin_memcpy(&lu, &l, 2);
    size_t off = foff(n, k, Kpad >> 5);
    hi[off] = hu; lo[off] = lu;
}

// f[G,300] f32 -> hi/lo [G,320] bf16 LINEAR (for the LDS-based k_logits)
__global__ void k_fsplit(const float* __restrict__ f, unsigned short* __restrict__ hi,
                         unsigned short* __restrict__ lo, int G) {
    int idx = blockIdx.x * blockDim.x + threadIdx.x;
    if (idx >= G * AGGP) return;
    int g = idx / AGGP, c = idx % AGGP;
    float v = (c < EMB) ? f[(size_t)g * EMB + c] : 0.f;
    bf16 h = __float2bfloat16(v);
    float rem = v - __bfloat162float(h);
    unsigned short hu; __builtin_memcpy(&hu, &h, 2);
    hi[idx] = hu;
    lo[idx] = f2bu(rem);
}

// ---------------- CSR build (dst-sorted edge ids) ----------------

__global__ void k_hist(const int* __restrict__ ei, int* __restrict__ deg, int E) {
    int e = blockIdx.x * blockDim.x + threadIdx.x;
    if (e < E) atomicAdd(&deg[ei[E + e]], 1);
}

__global__ void k_chunksum(const int* __restrict__ deg, int* __restrict__ csum, int total) {
    __shared__ int s[256];
    int t = threadIdx.x, i = blockIdx.x * 256 + t;
    s[t] = (i < total) ? deg[i] : 0;
    __syncthreads();
    for (int off = 128; off > 0; off >>= 1) {
        if (t < off) s[t] += s[t + off];
        __syncthreads();
    }
    if (t == 0) csum[blockIdx.x] = s[0];
}

__global__ void k_scanchunks(const int* __restrict__ csum, int* __restrict__ coff, int n) {
    if (threadIdx.x == 0) {
        int acc = 0;
        for (int b = 0; b < n; ++b) { coff[b] = acc; acc += csum[b]; }
    }
}

__global__ void k_scan2(const int* __restrict__ deg, const int* __restrict__ coff,
                        int* __restrict__ rowstart, int total) {
    __shared__ int s[256];
    int t = threadIdx.x, b = blockIdx.x, i = b * 256 + t;
    int v = (i < total) ? deg[i] : 0;
    s[t] = v;
    __syncthreads();
    for (int off = 1; off < 256; off <<= 1) {
        int u = (t >= off) ? s[t - off] : 0;
        __syncthreads();
        s[t] += u;
        __syncthreads();
    }
    if (i < total) rowstart[i] = coff[b] + s[t] - v;
}

__global__ void k_initcursor(const int* __restrict__ rowstart, int* __restrict__ cur, int N) {
    int i = blockIdx.x * blockDim.x + threadIdx.x;
    if (i < N) cur[i] = rowstart[i];
}

__global__ void k_fill(const int* __restrict__ ei, int* __restrict__ cur,
                       int* __restrict__ esorted, int E) {
    int e = blockIdx.x * blockDim.x + threadIdx.x;
    if (e < E) {
        int p = atomicAdd(&cur[ei[E + e]], 1);
        esorted[p] = e;
    }
}

// packed[p] = src | (combo<<17), combo = a0*3+a1 (18 combos; self-loop=12)
__global__ void k_pack(const int* __restrict__ ei, const int* __restrict__ ea,
                       const int* __restrict__ esorted, int* __restrict__ packed, int E) {
    int p = blockIdx.x * blockDim.x + threadIdx.x;
    if (p >= E) return;
    int e = esorted[p];
    int s = ei[e];
    int cb = ea[2 * e] * 3 + ea[2 * e + 1];
    packed[p] = s | (cb << 17);
}

// canonical per-bucket order -> deterministic fp32 aggregation sum order
__global__ void k_sortb(const int* __restrict__ rowstart, int* __restrict__ packed, int N) {
    int n = blockIdx.x * blockDim.x + threadIdx.x;
    if (n >= N) return;
    int p0 = rowstart[n], p1 = rowstart[n + 1];
    for (int i = p0 + 1; i < p1; ++i) {
        int v = packed[i];
        int j = i - 1;
        while (j >= p0 && packed[j] > v) { packed[j + 1] = packed[j]; --j; }
        packed[j + 1] = v;
    }
}

__global__ void k_gstart(const int* __restrict__ batch, int* __restrict__ gstart, int N) {
    int g = blockIdx.x * blockDim.x + threadIdx.x;
    if (g > NGRAPH) return;
    int lo = 0, hi = N;
    while (lo < hi) { int mid = (lo + hi) >> 1; if (batch[mid] < g) lo = mid + 1; else hi = mid; }
    gstart[g] = lo;
}

// per-layer combo table: cmb[cb][300] = e1[cb/3] + e2[cb%3]  (fp32)
__global__ void k_combo(const float4* __restrict__ e1, const float4* __restrict__ e2,
                        float4* __restrict__ cmb) {
    int t = blockIdx.x * blockDim.x + threadIdx.x;
    if (t >= 18 * EMBC) return;
    int cb = t / EMBC, j = t % EMBC;
    float4 u = e1[(cb / 3) * EMBC + j];
    float4 v = e2[(cb % 3) * EMBC + j];
    float4 r; r.x = u.x + v.x; r.y = u.y + v.y; r.z = u.z + v.z; r.w = u.w + v.w;
    cmb[t] = r;
}

// ---------------- node init & aggregation (with fused BN affine) ----------------

__global__ void k_init_h(const int* __restrict__ x,
                         const float4* __restrict__ ae1,
                         const float4* __restrict__ ae2,
                         bf4* __restrict__ h4, int N) {
    int idx = blockIdx.x * blockDim.x + threadIdx.x;
    if (idx >= N * EMBC) return;
    int i = idx / EMBC, j = idx % EMBC;
    int a0 = x[2 * i], a1 = x[2 * i + 1];
    float4 u = ae1[a0 * EMBC + j];
    float4 v = ae2[a1 * EMBC + j];
    bf4 r = { f2b(u.x + v.x), f2b(u.y + v.y), f2b(u.z + v.z), f2b(u.w + v.w) };
    h4[idx] = r;
}

// agg[n] = act(h[n]) + cmb[12] + sum_p(...) ; written FRAGMENT-MAJOR (nks=10)
__global__ void k_aggregate(const bf4* __restrict__ h4,
                            const int* __restrict__ packed,
                            const float4* __restrict__ cmb,   // [18,75]
                            const int* __restrict__ rowstart,
                            const float* __restrict__ stats, int use_aff,
                            bf4* __restrict__ aggf, int N) {
    int idx = blockIdx.x * blockDim.x + threadIdx.x;
    if (idx >= N * AGGC) return;
    int n = idx / AGGC, j = idx % AGGC;
    // fragment slot for k = 4j..4j+3 (8B aligned)
    size_t off = foff(n, 4 * j, 10);
    if (j >= EMBC) {
        bf4 z = { f2b(0.f), f2b(0.f), f2b(0.f), f2b(0.f) };
        aggf[off >> 2] = z;
        return;
    }
    float4 sc = make_float4(1.f, 1.f, 1.f, 1.f);
    float4 sh = make_float4(0.f, 0.f, 0.f, 0.f);
    if (use_aff) {
        sc = ((const float4*)stats)[j];
        sh = ((const float4*)(stats + EMB))[j];
    }
    bf4 hv = h4[(size_t)n * EMBC + j];
    float hx = b2f(hv.x), hy = b2f(hv.y), hz = b2f(hv.z), hw = b2f(hv.w);
    if (use_aff) {
        hx = fmaxf(hx * sc.x + sh.x, 0.f); hy = fmaxf(hy * sc.y + sh.y, 0.f);
        hz = fmaxf(hz * sc.z + sh.z, 0.f); hw = fmaxf(hw * sc.w + sh.w, 0.f);
    }
    float4 s0 = cmb[12 * EMBC + j];      // self-loop combo (edge_attr [4,0])
    float ax = hx + s0.x, ay = hy + s0.y, az = hz + s0.z, aw = hw + s0.w;
    int p0 = rowstart[n], p1 = rowstart[n + 1];
    for (int p = p0; p < p1; ++p) {
        int u = packed[p];
        int s = u & 131071;
        int cb = u >> 17;
        bf4 hs = h4[(size_t)s * EMBC + j];
        float gx = b2f(hs.x), gy = b2f(hs.y), gz = b2f(hs.z), gw = b2f(hs.w);
        if (use_aff) {
            gx = fmaxf(gx * sc.x + sh.x, 0.f); gy = fmaxf(gy * sc.y + sh.y, 0.f);
            gz = fmaxf(gz * sc.z + sh.z, 0.f); gw = fmaxf(gw * sc.w + sh.w, 0.f);
        }
        float4 cv = cmb[cb * EMBC + j];
        ax += gx + cv.x; ay += gy + cv.y;
        az += gz + cv.z; aw += gw + cv.w;
    }
    bf4 r = { f2b(ax), f2b(ay), f2b(az), f2b(aw) };
    aggf[off >> 2] = r;
}

// BN(h) copy for projector A: FRAGMENT-MAJOR (nks=10), pad zeroed
__global__ void k_bncopy(const bf4* __restrict__ h4, const float* __restrict__ stats,
                         bf4* __restrict__ dstf, int N) {
    int idx = blockIdx.x * blockDim.x + threadIdx.x;
    if (idx >= N * AGGC) return;
    int n = idx / AGGC, j = idx % AGGC;
    size_t off = foff(n, 4 * j, 10);
    if (j >= EMBC) {
        bf4 z = { f2b(0.f), f2b(0.f), f2b(0.f), f2b(0.f) };
        dstf[off >> 2] = z;
        return;
    }
    float4 sc = ((const float4*)stats)[j];
    float4 sh = ((const float4*)(stats + EMB))[j];
    bf4 v = h4[(size_t)n * EMBC + j];
    bf4 r = { f2b(b2f(v.x) * sc.x + sh.x), f2b(b2f(v.y) * sc.y + sh.y),
              f2b(b2f(v.z) * sc.z + sh.z), f2b(b2f(v.w) * sc.w + sh.w) };
    dstf[off >> 2] = r;
}

// ---------------- MFMA GEMM, fragment-major operands, no LDS, no barriers ------
// C[M,Nc] = A@(Bhi+Blo)^T + bias. A,B in fragment-major; per K-step each wave
// issues 8 coalesced 1KB loads (4 A-rowtiles + 2 B-coltiles x hi/lo) and 16
// MFMA; 1-deep register prefetch. Waves fully independent (latency hidden by
// 16 waves/CU). C written linear (nksC=0) or fragment-major (nksC=Kpad/32 of
// the CONSUMING gemm); frag mode writes all Npad cols (0 beyond Nc) so the
// consumer reads only freshly-written bytes.

#define GBM 128
#define GBN 64

__global__ __launch_bounds__(256, 4)
void k_gemm_mfma(const unsigned short* __restrict__ FA, int nks,
                 const unsigned short* __restrict__ Bhi,
                 const unsigned short* __restrict__ Blo,
                 const float* __restrict__ bias,
                 unsigned short* __restrict__ C, int ldc, int nksC,
                 int M, int Nc, int relu,
                 float* __restrict__ psum, int do_stats) {
    __shared__ float cred[512];               // stats scratch only (2 KB)

    int tid = threadIdx.x;
    int wv = tid >> 6, lane = tid & 63;
    int quad = lane >> 4, l16 = lane & 15;
    int wm = wv & 1, wn = wv >> 1;            // 2x2 wave grid of 64x32 tiles

    // XCD swizzle: col-tiles of one row-block get linear ids equal mod 8
    int ncols = gridDim.x, nrows = gridDim.y;
    int lin = blockIdx.y * ncols + blockIdx.x;
    int g = lin / (8 * ncols);
    int rem = lin - g * 8 * ncols;
    int rows_in = min(8, nrows - g * 8);
    int colb = rem / rows_in;
    int rowb = g * 8 + (rem - colb * rows_in);
    int row0 = rowb * GBM;
    int col0 = colb * GBN;

    int Mt = M >> 4;                          // M % 16 == 0 (N=100000)
    // per-lane fragment base pointers (coalesced: +lane*8 elems = lane*16B)
    const unsigned short* Ap[4];
    #pragma unroll
    for (int mt = 0; mt < 4; ++mt) {
        int rt = min((row0 >> 4) + 4 * wm + mt, Mt - 1);
        Ap[mt] = FA + (((size_t)rt * nks) << 9) + lane * 8;
    }
    const unsigned short* Bp[2];
    #pragma unroll
    for (int j = 0; j < 2; ++j) {
        int ct = (col0 >> 4) + 2 * wn + j;
        Bp[j] = Bhi + (((size_t)ct * nks) << 9) + lane * 8;
    }
    const size_t dBL = (size_t)(Blo - Bhi);

    float4v acc[4][2];
    #pragma unroll
    for (int i = 0; i < 4; ++i)
        #pragma unroll
        for (int j = 0; j < 2; ++j) acc[i][j] = (float4v){0.f, 0.f, 0.f, 0.f};

    // preload step 0
    short8 a[4], bh[2], bl[2];
    #pragma unroll
    for (int mt = 0; mt < 4; ++mt) a[mt] = *(const short8*)(Ap[mt]);
    #pragma unroll
    for (int j = 0; j < 2; ++j) {
        bh[j] = *(const short8*)(Bp[j]);
        bl[j] = *(const short8*)(Bp[j] + dBL);
    }

    for (int ks = 0; ks < nks; ++ks) {
        short8 an[4], bnh[2], bnl[2];
        bool more = (ks + 1 < nks);
        if (more) {
            size_t o = ((size_t)(ks + 1)) << 9;
            #pragma unroll
            for (int mt = 0; mt < 4; ++mt) an[mt] = *(const short8*)(Ap[mt] + o);
            #pragma unroll
            for (int j = 0; j < 2; ++j) {
                bnh[j] = *(const short8*)(Bp[j] + o);
                bnl[j] = *(const short8*)(Bp[j] + o + dBL);
            }
        }
        // MFMA: per accumulator the (hi,lo) chain in k order — identical
        // FP sequence to the verified LDS path.
        #pragma unroll
        for (int ntl = 0; ntl < 2; ++ntl) {
            #pragma unroll
            for (int mt = 0; mt < 4; ++mt) {
                acc[mt][ntl] = __builtin_amdgcn_mfma_f32_16x16x32_bf16(a[mt], bh[ntl], acc[mt][ntl], 0, 0, 0);
                acc[mt][ntl] = __builtin_amdgcn_mfma_f32_16x16x32_bf16(a[mt], bl[ntl], acc[mt][ntl], 0, 0, 0);
            }
        }
        if (more) {
            #pragma unroll
            for (int mt = 0; mt < 4; ++mt) a[mt] = an[mt];
            #pragma unroll
            for (int j = 0; j < 2; ++j) { bh[j] = bnh[j]; bl[j] = bnl[j]; }
        }
    }

    // epilogue: C/D layout col=lane&15, row=quad*4+reg
    float sv[2], qv[2];
    #pragma unroll
    for (int ntl = 0; ntl < 2; ++ntl) { sv[ntl] = 0.f; qv[ntl] = 0.f; }
    #pragma unroll
    for (int mt = 0; mt < 4; ++mt) {
        int rbase = row0 + 64 * wm + mt * 16 + quad * 4;
        #pragma unroll
        for (int ntl = 0; ntl < 2; ++ntl) {
            int c = col0 + 32 * wn + ntl * 16 + l16;
            if (!nksC && c >= Nc) continue;   // linear mode: skip pad cols
            float bs = (c < Nc) ? bias[c] : 0.f;
            #pragma unroll
            for (int i = 0; i < 4; ++i) {
                int r = rbase + i;
                if (r >= M) continue;
                float v = acc[mt][ntl][i] + bs;   // pad cols: acc==0, bs==0
                if (relu) v = fmaxf(v, 0.f);
                if (do_stats) { sv[ntl] += v; qv[ntl] += v * v; }
                if (nksC) C[foff(r, c, nksC)] = f2bu(v);
                else      C[(size_t)r * ldc + c] = f2bu(v);
            }
        }
    }
    if (do_stats) {
        #pragma unroll
        for (int ntl = 0; ntl < 2; ++ntl) {
            float s = sv[ntl], q = qv[ntl];
            s += __shfl_down(s, 32, 64); s += __shfl_down(s, 16, 64);
            q += __shfl_down(q, 32, 64); q += __shfl_down(q, 16, 64);
            if (quad == 0) {
                cred[wv * 64 + ntl * 16 + l16] = s;
                cred[256 + wv * 64 + ntl * 16 + l16] = q;
            }
        }
        __syncthreads();
        if (tid < 64) {
            // per-row-block partial: psum[rowb][c] = s, psum[rowb][384+c] = q
            int gc = tid >> 5, cin = tid & 31;
            float s = cred[(2 * gc) * 64 + cin] + cred[(2 * gc + 1) * 64 + cin];
            float q = cred[256 + (2 * gc) * 64 + cin] + cred[256 + (2 * gc + 1) * 64 + cin];
            int c = col0 + tid;
            psum[(size_t)rowb * 768 + c] = s;
            psum[(size_t)rowb * 768 + 384 + c] = q;
        }
    }
}

// ---------------- logits MFMA (unchanged LDS path, linear pitch-320 inputs) ----

__global__ __launch_bounds__(256)
void k_logits(const unsigned short* __restrict__ Ahg, const unsigned short* __restrict__ Alg,
              const unsigned short* __restrict__ Bhg, const unsigned short* __restrict__ Blg,
              float* __restrict__ C, float scale) {
    __shared__ unsigned short sAh[64][64];
    __shared__ unsigned short sAl[64][64];
    __shared__ unsigned short sBh[128][64];
    __shared__ unsigned short sBl[128][64];

    int tid = threadIdx.x;
    int wv = tid >> 6, lane = tid & 63;
    int quad = lane >> 4, l16 = lane & 15;
    int lrow = lane >> 3;
    int gchunk = (lane & 7) ^ lrow;
    int sw = lane & 7;
    int row0 = blockIdx.y * 64;
    int col0 = blockIdx.x * 128;

    float4v acc[8];
    #pragma unroll
    for (int j = 0; j < 8; ++j) acc[j] = (float4v){0.f, 0.f, 0.f, 0.f};

    for (int k0 = 0; k0 < AGGP; k0 += 64) {
        #pragma unroll
        for (int j = 0; j < 2; ++j) {
            int r = 16 * wv + 8 * j + lrow;
            size_t go = (size_t)(row0 + r) * AGGP + k0 + gchunk * 8;
            gl_lds16(Ahg + go, &sAh[16 * wv + 8 * j][0]);
            gl_lds16(Alg + go, &sAl[16 * wv + 8 * j][0]);
        }
        #pragma unroll
        for (int j = 0; j < 4; ++j) {
            int r = 32 * wv + 8 * j + lrow;
            size_t go = (size_t)(col0 + r) * AGGP + k0 + gchunk * 8;
            gl_lds16(Bhg + go, &sBh[32 * wv + 8 * j][0]);
            gl_lds16(Blg + go, &sBl[32 * wv + 8 * j][0]);
        }
        __syncthreads();

        #pragma unroll
        for (int ks = 0; ks < 64; ks += 32) {
            int pcl = ((ks >> 3) + quad) ^ sw;
            short8 ah = *(const short8*)(&sAh[wv * 16 + l16][pcl * 8]);
            short8 al = *(const short8*)(&sAl[wv * 16 + l16][pcl * 8]);
            #pragma unroll
            for (int nt = 0; nt < 8; ++nt) {
                short8 bh = *(const short8*)(&sBh[nt * 16 + l16][pcl * 8]);
                short8 bl = *(const short8*)(&sBl[nt * 16 + l16][pcl * 8]);
                acc[nt] = __builtin_amdgcn_mfma_f32_16x16x32_bf16(ah, bh, acc[nt], 0, 0, 0);
                acc[nt] = __builtin_amdgcn_mfma_f32_16x16x32_bf16(ah, bl, acc[nt], 0, 0, 0);
                acc[nt] = __builtin_amdgcn_mfma_f32_16x16x32_bf16(al, bh, acc[nt], 0, 0, 0);
            }
        }
        __syncthreads();
    }

    int rbase = row0 + wv * 16 + quad * 4;
    #pragma unroll
    for (int nt = 0; nt < 8; ++nt) {
        int c = col0 + nt * 16 + l16;
        #pragma unroll
        for (int i = 0; i < 4; ++i)
            C[(size_t)(rbase + i) * NGRAPH + c] = acc[nt][i] * scale;
    }
}

// ---------------- BN stats reduction (deterministic, two-stage) ----------------

__global__ void k_statred(const float* __restrict__ psum, float* __restrict__ part2, int nrb) {
    int b = blockIdx.x, c = threadIdx.x;   // 768 threads
    float acc = 0.f;
    for (int r = b; r < nrb; r += NRED) acc += psum[(size_t)r * 768 + c];
    part2[b * 768 + c] = acc;
}

__global__ void k_bn_prep(const float* __restrict__ part2, float* __restrict__ stats,
                          const float* __restrict__ gamma, const float* __restrict__ beta,
                          float invN) {
    int c = threadIdx.x;
    if (c >= EMB) return;
    float s = 0.f, q = 0.f;
    for (int b = 0; b < NRED; ++b) {
        s += part2[b * 768 + c];
        q += part2[b * 768 + 384 + c];
    }
    float mean = s * invN;
    float var = q * invN - mean * mean;
    float scale = gamma[c] * rsqrtf(var + BN_EPS);
    stats[c] = scale;
    stats[EMB + c] = beta[c] - mean * scale;
}

// ---------------- fused pool + mean + L2 normalize (proj pitch 320) ----------------

__global__ void k_poolnorm(const bf16* __restrict__ proj, const int* __restrict__ gstart,
                           float* __restrict__ f) {
    int g = blockIdx.x, t = threadIdx.x;
    int s = gstart[g], e = gstart[g + 1];
    float sum = 0.f;
    if (t < EMB)
        for (int r = s; r < e; ++r) sum += b2f(proj[(size_t)r * AGGP + t]);
    float cnt = fmaxf((float)(e - s), 1.f);
    float m = sum / cnt;
    float q = (t < EMB) ? m * m : 0.f;
    for (int off = 32; off > 0; off >>= 1) q += __shfl_down(q, off, 64);
    __shared__ float red[5];
    int lane = t & 63, wid = t >> 6;
    if (lane == 0) red[wid] = q;
    __syncthreads();
    float tot = red[0] + red[1] + red[2] + red[3] + red[4];
    float invn = 1.f / fmaxf(sqrtf(tot), 1e-12f);
    if (t < EMB) f[(size_t)g * EMB + t] = m * invn;
}

// ---------------- host ----------------

static inline int ceil_div(int a, int b) { return (a + b - 1) / b; }

extern "C" void kernel_launch(void* const* d_in, const int* in_sizes, int n_in,
                              void* d_out, int out_size, void* d_ws, size_t ws_size,
                              hipStream_t stream) {
    const int N = in_sizes[0] / 2;    // 100000
    const int E = in_sizes[1] / 2;    // 400000

    const int* x[2]  = { (const int*)d_in[0], (const int*)d_in[4] };
    const int* ei[2] = { (const int*)d_in[1], (const int*)d_in[5] };
    const int* ea[2] = { (const int*)d_in[2], (const int*)d_in[6] };
    const int* bt[2] = { (const int*)d_in[3], (const int*)d_in[7] };
    const float* atom1 = (const float*)d_in[8];
    const float* atom2 = (const float*)d_in[9];
    const float* ee1 = (const float*)d_in[10];   // [5,6,300]
    const float* ee2 = (const float*)d_in[11];   // [5,3,300]
    const float* w1  = (const float*)d_in[12];   // [5,300,600]
    const float* b1  = (const float*)d_in[13];   // [5,600]
    const float* w2  = (const float*)d_in[14];   // [5,600,300]
    const float* b2  = (const float*)d_in[15];   // [5,300]
    const float* gam = (const float*)d_in[16];
    const float* bet = (const float*)d_in[17];
    const float* pw  = (const float*)d_in[18];   // [300,300]
    const float* pb  = (const float*)d_in[19];
    float* out = (float*)d_out;

    // ---- workspace ----
    char* wsb = (char*)d_ws;
    bf16* h     = (bf16*)(wsb);                  // linear [N,300]
    bf16* aggf  = (bf16*)(wsb + 60000000);       // frag [6250][10] (64MB)
    bf16* hidf  = (bf16*)(wsb + 124000000);      // frag [6250][20] (128MB)
    bf16* projl = (bf16*)(wsb + 124000000);      // linear [N,320] (reuse, dead hidf)
    // f-splits for logits reuse the (dead) hidf region
    unsigned short* f0hi = (unsigned short*)(wsb + 124000000);
    unsigned short* f0lo = (unsigned short*)(wsb + 126621440);
    unsigned short* f1hi = (unsigned short*)(wsb + 129242880);
    unsigned short* f1lo = (unsigned short*)(wsb + 131864320);

    // ---- d_out scratch (consumed before logits GEMM) ----
    int* deg      = (int*)d_out;              // N+1
    int* rowstart = deg + (N + 1);            // N+1
    int* cursor   = rowstart + (N + 1);       // N
    int* esorted  = cursor + N;               // E
    int* packed   = esorted + E;              // E
    int* csum     = packed + E;               // 512
    int* coff     = csum + 512;               // 512
    int* gstart   = coff + 512;               // 4097
    float* stats  = (float*)(gstart + 4097);  // 600
    float* cmb    = stats + 600;              // 18*300
    char* splits  = (char*)d_out + 4500224;   // 256B-aligned
    unsigned short* w1hi = (unsigned short*)(splits);               // 5*[640][320] frag
    unsigned short* w1lo = (unsigned short*)(splits + 2048000);
    unsigned short* w2hi = (unsigned short*)(splits + 4096000);     // 5*[384][640] frag
    unsigned short* w2lo = (unsigned short*)(splits + 6553600);
    unsigned short* pjhi = (unsigned short*)(splits + 9011200);     // [384][320] frag
    unsigned short* pjlo = (unsigned short*)(splits + 9256960);
    float* psum  = (float*)((char*)d_out + 20971520);               // [782][768]
    float* part2 = (float*)((char*)d_out + 25165824);               // [NRED][768]
    float* f0    = (float*)((char*)d_out + 33554432);               // [4096,300]
    float* f1    = (float*)((char*)d_out + 38469632);               // [4096,300]

    const int TB = 256;
    const int nh_blocks = ceil_div(N * EMBC, TB);
    const int na_blocks = ceil_div(N * AGGC, TB);
    const int nchunks = ceil_div(N + 1, 256);
    const float invN = 1.f / (float)N;

    // ---- split all weights into fragment-major (once; shared by both branches) ----
    for (int l = 0; l < 5; ++l) {
        k_split<<<ceil_div(640 * 320, TB), TB, 0, stream>>>(
            w1 + (size_t)l * EMB * HID, EMB, HID, 320, 640,
            w1hi + (size_t)l * 640 * 320, w1lo + (size_t)l * 640 * 320);
        k_split<<<ceil_div(384 * 640, TB), TB, 0, stream>>>(
            w2 + (size_t)l * HID * EMB, HID, EMB, 640, 384,
            w2hi + (size_t)l * 384 * 640, w2lo + (size_t)l * 384 * 640);
    }
    k_split<<<ceil_div(384 * 320, TB), TB, 0, stream>>>(pw, EMB, EMB, 320, 384, pjhi, pjlo);

    const int mrows = ceil_div(N, GBM);       // 782
    dim3 g1(10, mrows);   // GEMM1: Npad=640 (64-col tiles)
    dim3 g2(6, mrows);    // GEMM2/proj: Npad=384
    dim3 glg(32, 64);     // logits

    for (int br = 0; br < 2; ++br) {
        float* fout = br == 0 ? f0 : f1;
        // ---- CSR build + packed edges (canonical per-bucket order) ----
        k_zero_i<<<ceil_div(N + 1, TB), TB, 0, stream>>>(deg, N + 1);
        k_hist<<<ceil_div(E, TB), TB, 0, stream>>>(ei[br], deg, E);
        k_chunksum<<<nchunks, 256, 0, stream>>>(deg, csum, N + 1);
        k_scanchunks<<<1, 64, 0, stream>>>(csum, coff, nchunks);
        k_scan2<<<nchunks, 256, 0, stream>>>(deg, coff, rowstart, N + 1);
        k_initcursor<<<ceil_div(N, TB), TB, 0, stream>>>(rowstart, cursor, N);
        k_fill<<<ceil_div(E, TB), TB, 0, stream>>>(ei[br], cursor, esorted, E);
        k_pack<<<ceil_div(E, TB), TB, 0, stream>>>(ei[br], ea[br], esorted, packed, E);
        k_sortb<<<ceil_div(N, TB), TB, 0, stream>>>(rowstart, packed, N);
        k_gstart<<<ceil_div(NGRAPH + 1, TB), TB, 0, stream>>>(bt[br], gstart, N);
        // ---- encoder ----
        k_init_h<<<nh_blocks, TB, 0, stream>>>(x[br], (const float4*)atom1,
                                               (const float4*)atom2, (bf4*)h, N);
        for (int l = 0; l < 5; ++l) {
            k_combo<<<ceil_div(18 * EMBC, TB), TB, 0, stream>>>(
                (const float4*)(ee1 + (size_t)l * 6 * EMB),
                (const float4*)(ee2 + (size_t)l * 3 * EMB), (float4*)cmb);
            k_aggregate<<<na_blocks, TB, 0, stream>>>((const bf4*)h, packed,
                                                      (const float4*)cmb, rowstart,
                                                      stats, l > 0, (bf4*)aggf, N);
            // GEMM1: aggf(frag,nks=10) @ w1^T -> hidf (frag for GEMM2, nksC=20)
            k_gemm_mfma<<<g1, 256, 0, stream>>>(
                (const unsigned short*)aggf, 10,
                w1hi + (size_t)l * 640 * 320, w1lo + (size_t)l * 640 * 320,
                b1 + (size_t)l * HID, (unsigned short*)hidf, 0, 20,
                N, HID, 1, nullptr, 0);
            // GEMM2: hidf(frag,nks=20) @ w2^T -> h linear [N,300], + stats
            k_gemm_mfma<<<g2, 256, 0, stream>>>(
                (const unsigned short*)hidf, 20,
                w2hi + (size_t)l * 384 * 640, w2lo + (size_t)l * 384 * 640,
                b2 + (size_t)l * EMB, (unsigned short*)h, EMB, 0,
                N, EMB, 0, psum, 1);
            k_statred<<<NRED, 768, 0, stream>>>(psum, part2, mrows);
            k_bn_prep<<<1, 320, 0, stream>>>(part2, stats, gam + (size_t)l * EMB,
                                             bet + (size_t)l * EMB, invN);
        }
        // BN(h) -> fragment-major projector A (into aggf region, dead)
        k_bncopy<<<na_blocks, TB, 0, stream>>>((const bf4*)h, stats, (bf4*)aggf, N);
        // projector: aggf(frag,nks=10) @ pj^T -> projl linear [N,320]
        k_gemm_mfma<<<g2, 256, 0, stream>>>(
            (const unsigned short*)aggf, 10, pjhi, pjlo, pb,
            (unsigned short*)projl, AGGP, 0, N, EMB, 0, nullptr, 0);
        // fused pool + mean + L2 norm
        k_poolnorm<<<NGRAPH, 320, 0, stream>>>(projl, gstart, fout);
    }
    // ---- logits: split f0/f1 (hidf region now dead), 3-pass MFMA ----
    k_fsplit<<<ceil_div(NGRAPH * AGGP, TB), TB, 0, stream>>>(f0, f0hi, f0lo, NGRAPH);
    k_fsplit<<<ceil_div(NGRAPH * AGGP, TB), TB, 0, stream>>>(f1, f1hi, f1lo, NGRAPH);
    k_logits<<<glg, 256, 0, stream>>>(f0hi, f0lo, f1hi, f1lo, out, INV_TEMP);
}